// Round 2
// baseline (97.206 us; speedup 1.0000x reference)
//
#include <hip/hip_runtime.h>
#include <math.h>

#define NBLK 2048
#define NTHR 256
#define NWAVE (NTHR / 64)
#define COUNTER_OFF (NBLK * sizeof(float2))  // counter lives after partials in d_ws

// Fused: grid-stride float4 reduction -> per-block partials -> last block
// finalizes (deterministic fixed-order sum) and evaluates the closed form.
__global__ __launch_bounds__(NTHR) void grt_fused_kernel(
    const float* __restrict__ x, int n4,
    float2* __restrict__ part, unsigned int* __restrict__ counter,
    const float* __restrict__ log_sw, const float* __restrict__ log_sz,
    const float* __restrict__ log_sx, float* __restrict__ out, float dn) {
    const float4* __restrict__ x4 = reinterpret_cast<const float4*>(x);
    const int tid = blockIdx.x * NTHR + threadIdx.x;
    const int stride = gridDim.x * NTHR;

    // 4 independent accumulator pairs -> 4 loads in flight, short dep chains.
    float s0 = 0.f, s1 = 0.f, s2 = 0.f, s3 = 0.f;
    float q0 = 0.f, q1 = 0.f, q2 = 0.f, q3 = 0.f;
    int i = tid;
    for (; i + 3 * stride < n4; i += 4 * stride) {
        float4 a = x4[i];
        float4 b = x4[i + stride];
        float4 c = x4[i + 2 * stride];
        float4 d = x4[i + 3 * stride];
        s0 += a.x + a.y + a.z + a.w;
        s1 += b.x + b.y + b.z + b.w;
        s2 += c.x + c.y + c.z + c.w;
        s3 += d.x + d.y + d.z + d.w;
        q0 = fmaf(a.x, a.x, q0); q0 = fmaf(a.y, a.y, q0);
        q0 = fmaf(a.z, a.z, q0); q0 = fmaf(a.w, a.w, q0);
        q1 = fmaf(b.x, b.x, q1); q1 = fmaf(b.y, b.y, q1);
        q1 = fmaf(b.z, b.z, q1); q1 = fmaf(b.w, b.w, q1);
        q2 = fmaf(c.x, c.x, q2); q2 = fmaf(c.y, c.y, q2);
        q2 = fmaf(c.z, c.z, q2); q2 = fmaf(c.w, c.w, q2);
        q3 = fmaf(d.x, d.x, q3); q3 = fmaf(d.y, d.y, q3);
        q3 = fmaf(d.z, d.z, q3); q3 = fmaf(d.w, d.w, q3);
    }
    for (; i < n4; i += stride) {
        float4 a = x4[i];
        s0 += a.x + a.y + a.z + a.w;
        q0 = fmaf(a.x, a.x, q0); q0 = fmaf(a.y, a.y, q0);
        q0 = fmaf(a.z, a.z, q0); q0 = fmaf(a.w, a.w, q0);
    }
    float s = (s0 + s1) + (s2 + s3);
    float q = (q0 + q1) + (q2 + q3);

    // Wave (64-lane) shuffle reduction.
    #pragma unroll
    for (int off = 32; off > 0; off >>= 1) {
        s += __shfl_down(s, off, 64);
        q += __shfl_down(q, off, 64);
    }

    __shared__ float2 lds[NWAVE];
    __shared__ int is_last;
    const int lane = threadIdx.x & 63;
    const int wave = threadIdx.x >> 6;
    if (lane == 0) lds[wave] = make_float2(s, q);
    __syncthreads();

    if (threadIdx.x == 0) {
        float2 acc = lds[0];
        #pragma unroll
        for (int w = 1; w < NWAVE; ++w) {
            acc.x += lds[w].x;
            acc.y += lds[w].y;
        }
        part[blockIdx.x] = acc;
        __threadfence();  // make partial visible device-wide before the count
        unsigned int old = atomicAdd(counter, 1u);
        is_last = (old == (unsigned int)(gridDim.x - 1));
    }
    __syncthreads();

    if (is_last) {
        __threadfence();  // acquire: see all other blocks' partials
        float fs = 0.f, fq = 0.f;
        for (int p = threadIdx.x; p < NBLK; p += NTHR) {
            float2 v = part[p];
            fs += v.x;
            fq += v.y;
        }
        #pragma unroll
        for (int off = 32; off > 0; off >>= 1) {
            fs += __shfl_down(fs, off, 64);
            fq += __shfl_down(fq, off, 64);
        }
        __syncthreads();  // lds reuse hazard
        if (lane == 0) lds[wave] = make_float2(fs, fq);
        __syncthreads();
        if (threadIdx.x == 0) {
            double ss = 0.0, qq = 0.0;
            #pragma unroll
            for (int w = 0; w < NWAVE; ++w) {
                ss += (double)lds[w].x;
                qq += (double)lds[w].y;
            }
            double n = (double)dn;
            double b = exp(2.0 * (double)log_sw[0]);
            double a = exp(2.0 * (double)log_sz[0]) + exp(2.0 * (double)log_sx[0]);
            double quad = qq / a - b * ss * ss / (a * (a + n * b));
            double logdet = (n - 1.0) * log(a) + log(a + n * b);
            const double LOG_2PI = 1.837877066409345483560659472811;
            out[0] = (float)(-0.5 * (n * LOG_2PI + logdet + quad));
        }
    }
}

extern "C" void kernel_launch(void* const* d_in, const int* in_sizes, int n_in,
                              void* d_out, int out_size, void* d_ws, size_t ws_size,
                              hipStream_t stream) {
    const float* x      = (const float*)d_in[0];
    const float* log_sw = (const float*)d_in[1];
    const float* log_sz = (const float*)d_in[2];
    const float* log_sx = (const float*)d_in[3];
    float* out = (float*)d_out;
    int n = in_sizes[0];  // 33554432
    int n4 = n >> 2;

    float2* part = (float2*)d_ws;
    unsigned int* counter = (unsigned int*)((char*)d_ws + COUNTER_OFF);

    hipMemsetAsync(counter, 0, sizeof(unsigned int), stream);
    grt_fused_kernel<<<NBLK, NTHR, 0, stream>>>(x, n4, part, counter, log_sw,
                                                log_sz, log_sx, out, (float)n);
}

// Round 3
// 29.622 us; speedup vs baseline: 3.2816x; 3.2816x over previous
//
#include <hip/hip_runtime.h>
#include <math.h>

#define NBLK 2048
#define NTHR 256
#define NWAVE (NTHR / 64)

// Kernel 1: grid-stride float4 reduction, 4 independent accumulator streams
// (4 global_load_dwordx4 in flight per thread), per-block (sum, sumsq) partial.
__global__ __launch_bounds__(NTHR) void grt_partial_kernel(
    const float* __restrict__ x, float2* __restrict__ part, int n4) {
    const float4* __restrict__ x4 = reinterpret_cast<const float4*>(x);
    const int tid = blockIdx.x * NTHR + threadIdx.x;
    const int stride = NBLK * NTHR;

    float s0 = 0.f, s1 = 0.f, s2 = 0.f, s3 = 0.f;
    float q0 = 0.f, q1 = 0.f, q2 = 0.f, q3 = 0.f;
    int i = tid;
    for (; i + 3 * stride < n4; i += 4 * stride) {
        float4 a = x4[i];
        float4 b = x4[i + stride];
        float4 c = x4[i + 2 * stride];
        float4 d = x4[i + 3 * stride];
        s0 += a.x + a.y + a.z + a.w;
        s1 += b.x + b.y + b.z + b.w;
        s2 += c.x + c.y + c.z + c.w;
        s3 += d.x + d.y + d.z + d.w;
        q0 = fmaf(a.x, a.x, q0); q0 = fmaf(a.y, a.y, q0);
        q0 = fmaf(a.z, a.z, q0); q0 = fmaf(a.w, a.w, q0);
        q1 = fmaf(b.x, b.x, q1); q1 = fmaf(b.y, b.y, q1);
        q1 = fmaf(b.z, b.z, q1); q1 = fmaf(b.w, b.w, q1);
        q2 = fmaf(c.x, c.x, q2); q2 = fmaf(c.y, c.y, q2);
        q2 = fmaf(c.z, c.z, q2); q2 = fmaf(c.w, c.w, q2);
        q3 = fmaf(d.x, d.x, q3); q3 = fmaf(d.y, d.y, q3);
        q3 = fmaf(d.z, d.z, q3); q3 = fmaf(d.w, d.w, q3);
    }
    for (; i < n4; i += stride) {
        float4 a = x4[i];
        s0 += a.x + a.y + a.z + a.w;
        q0 = fmaf(a.x, a.x, q0); q0 = fmaf(a.y, a.y, q0);
        q0 = fmaf(a.z, a.z, q0); q0 = fmaf(a.w, a.w, q0);
    }
    float s = (s0 + s1) + (s2 + s3);
    float q = (q0 + q1) + (q2 + q3);

    #pragma unroll
    for (int off = 32; off > 0; off >>= 1) {
        s += __shfl_down(s, off, 64);
        q += __shfl_down(q, off, 64);
    }

    __shared__ float2 lds[NWAVE];
    const int lane = threadIdx.x & 63;
    const int wave = threadIdx.x >> 6;
    if (lane == 0) lds[wave] = make_float2(s, q);
    __syncthreads();

    if (threadIdx.x == 0) {
        float2 acc = lds[0];
        #pragma unroll
        for (int w = 1; w < NWAVE; ++w) {
            acc.x += lds[w].x;
            acc.y += lds[w].y;
        }
        part[blockIdx.x] = acc;
    }
}

// Kernel 2: single wave (no LDS, no syncthreads). Partials read as float4
// (pairs of float2): v = (s_even, q_even, s_odd, q_odd).
__global__ __launch_bounds__(64) void grt_final_kernel(
    const float4* __restrict__ part4,  // NBLK/2 float4
    const float* __restrict__ log_sw, const float* __restrict__ log_sz,
    const float* __restrict__ log_sx, float* __restrict__ out, float dn) {
    float s = 0.f, q = 0.f;
    #pragma unroll 4
    for (int i = threadIdx.x; i < NBLK / 2; i += 64) {
        float4 v = part4[i];
        s += v.x + v.z;
        q += v.y + v.w;
    }

    #pragma unroll
    for (int off = 32; off > 0; off >>= 1) {
        s += __shfl_down(s, off, 64);
        q += __shfl_down(q, off, 64);
    }

    if (threadIdx.x == 0) {
        double ss = (double)s, qq = (double)q;
        double n = (double)dn;
        double b = exp(2.0 * (double)log_sw[0]);
        double a = exp(2.0 * (double)log_sz[0]) + exp(2.0 * (double)log_sx[0]);
        double quad = qq / a - b * ss * ss / (a * (a + n * b));
        double logdet = (n - 1.0) * log(a) + log(a + n * b);
        const double LOG_2PI = 1.837877066409345483560659472811;
        out[0] = (float)(-0.5 * (n * LOG_2PI + logdet + quad));
    }
}

extern "C" void kernel_launch(void* const* d_in, const int* in_sizes, int n_in,
                              void* d_out, int out_size, void* d_ws, size_t ws_size,
                              hipStream_t stream) {
    const float* x      = (const float*)d_in[0];
    const float* log_sw = (const float*)d_in[1];
    const float* log_sz = (const float*)d_in[2];
    const float* log_sx = (const float*)d_in[3];
    float* out = (float*)d_out;
    int n = in_sizes[0];  // 33554432
    int n4 = n >> 2;

    float2* part = (float2*)d_ws;  // 2048 float2 = 16 KiB

    grt_partial_kernel<<<NBLK, NTHR, 0, stream>>>(x, part, n4);
    grt_final_kernel<<<1, 64, 0, stream>>>((const float4*)part, log_sw, log_sz,
                                           log_sx, out, (float)n);
}